// Round 1
// baseline (325.794 us; speedup 1.0000x reference)
//
#include <hip/hip_runtime.h>

#define NLOC  10
#define NGI   13
#define NPAIR 55   // nloc*(nloc+1)/2

// Precompute prodN[p][g] = n[i,g]*n[j,g] for pair p=(i,j), i<=j.
__global__ void prodn_kernel(const float* __restrict__ nmat, float* __restrict__ prodN) {
    int idx = blockIdx.x * blockDim.x + threadIdx.x;
    if (idx >= NPAIR * NGI) return;
    int p = idx / NGI, g = idx - p * NGI;
    int i = 0, rem = p;
    while (rem >= NLOC - i) { rem -= NLOC - i; ++i; }
    int j = i + rem;
    prodN[idx] = nmat[i * NGI + g] * nmat[j * NGI + g];
}

__global__ __launch_bounds__(256) void fem_kernel(
    const float* __restrict__ r0_in,
    const float* __restrict__ c_i,
    const float* __restrict__ c_n,
    const float* __restrict__ kp,
    const float* __restrict__ dtp,
    const float* __restrict__ nx,
    const float* __restrict__ detwei,
    const float* __restrict__ prodN,
    float* __restrict__ out,
    int nele)
{
    int e = blockIdx.x * blockDim.x + threadIdx.x;
    if (e >= nele) return;

    const float kk  = kp[0];
    const float idt = 1.0f / dtp[0];

    // s[g] = sqrt(detwei[e,g]); rows scaled by s so nxnx_ij = dot(row_i, row_j)
    float s[NGI];
    {
        const float* dwp = detwei + (size_t)e * NGI;
        #pragma unroll
        for (int g = 0; g < NGI; ++g) s[g] = sqrtf(dwp[g]);
    }

    float acc[NPAIR];
    #pragma unroll
    for (int p = 0; p < NPAIR; ++p) acc[p] = 0.0f;

    const float* base = nx + (size_t)e * (2 * NLOC * NGI);  // 260 floats, 16B-aligned

    // ---------------- spatial dim 0: floats [0,130) ----------------
    {
        float r[NLOC * NGI];
        #pragma unroll
        for (int q = 0; q < 32; ++q) {
            float4 v = reinterpret_cast<const float4*>(base)[q];
            r[4*q+0] = v.x; r[4*q+1] = v.y; r[4*q+2] = v.z; r[4*q+3] = v.w;
        }
        {
            float2 v = reinterpret_cast<const float2*>(base)[64];
            r[128] = v.x; r[129] = v.y;
        }
        #pragma unroll
        for (int l = 0; l < NLOC; ++l)
            #pragma unroll
            for (int g = 0; g < NGI; ++g)
                r[l*NGI+g] *= s[g];
        int p = 0;
        #pragma unroll
        for (int i = 0; i < NLOC; ++i)
            #pragma unroll
            for (int j = i; j < NLOC; ++j) {
                float a = acc[p];
                #pragma unroll
                for (int g = 0; g < NGI; ++g)
                    a = fmaf(r[i*NGI+g], r[j*NGI+g], a);
                acc[p] = a;
                ++p;
            }
    }
    // ---------------- spatial dim 1: floats [130,260) ----------------
    {
        float r[NLOC * NGI];
        {
            float2 v = reinterpret_cast<const float2*>(base)[65];
            r[0] = v.x; r[1] = v.y;
        }
        #pragma unroll
        for (int q = 0; q < 32; ++q) {
            float4 v = reinterpret_cast<const float4*>(base + 132)[q];  // byte 528: 16B-aligned
            r[2+4*q+0] = v.x; r[2+4*q+1] = v.y; r[2+4*q+2] = v.z; r[2+4*q+3] = v.w;
        }
        #pragma unroll
        for (int l = 0; l < NLOC; ++l)
            #pragma unroll
            for (int g = 0; g < NGI; ++g)
                r[l*NGI+g] *= s[g];
        int p = 0;
        #pragma unroll
        for (int i = 0; i < NLOC; ++i)
            #pragma unroll
            for (int j = i; j < NLOC; ++j) {
                float a = acc[p];
                #pragma unroll
                for (int g = 0; g < NGI; ++g)
                    a = fmaf(r[i*NGI+g], r[j*NGI+g], a);
                acc[p] = a;
                ++p;
            }
    }

    // ---------------- epilogue ----------------
    float dwv[NGI];
    #pragma unroll
    for (int g = 0; g < NGI; ++g) dwv[g] = s[g] * s[g];

    float ci[NLOC], cn[NLOC], rr[NLOC];
    {
        const float2* p2 = reinterpret_cast<const float2*>(c_i) + (size_t)e * 5;
        #pragma unroll
        for (int q = 0; q < 5; ++q) { float2 v = p2[q]; ci[2*q] = v.x; ci[2*q+1] = v.y; }
    }
    {
        const float2* p2 = reinterpret_cast<const float2*>(c_n) + (size_t)e * 5;
        #pragma unroll
        for (int q = 0; q < 5; ++q) { float2 v = p2[q]; cn[2*q] = v.x; cn[2*q+1] = v.y; }
    }
    {
        const float2* p2 = reinterpret_cast<const float2*>(r0_in) + (size_t)e * 5;
        #pragma unroll
        for (int q = 0; q < 5; ++q) { float2 v = p2[q]; rr[2*q] = v.x; rr[2*q+1] = v.y; }
    }

    float bd[NLOC * NLOC];
    {
        int p = 0;
        #pragma unroll
        for (int i = 0; i < NLOC; ++i)
            #pragma unroll
            for (int j = i; j < NLOC; ++j) {
                float nnv = 0.0f;
                #pragma unroll
                for (int g = 0; g < NGI; ++g)
                    nnv = fmaf(prodN[p*NGI+g], dwv[g], nnv);   // wave-uniform scalar operand
                float nndt = nnv * idt;
                float A = fmaf(acc[p], kk, nndt);
                bd[i*NLOC+j] = A;
                rr[i] = fmaf(nndt, cn[j], rr[i]);
                rr[i] = fmaf(-A, ci[j], rr[i]);
                if (i != j) {
                    bd[j*NLOC+i] = A;
                    rr[j] = fmaf(nndt, cn[i], rr[j]);
                    rr[j] = fmaf(-A, ci[i], rr[j]);
                }
                ++p;
            }
    }

    float* out_bd = out;
    float* out_dg = out + (size_t)nele * 100;
    float* out_r0 = out + (size_t)nele * 110;

    {
        float4* ob = reinterpret_cast<float4*>(out_bd + (size_t)e * 100);
        #pragma unroll
        for (int q = 0; q < 25; ++q)
            ob[q] = make_float4(bd[4*q], bd[4*q+1], bd[4*q+2], bd[4*q+3]);
    }
    {
        float2* od = reinterpret_cast<float2*>(out_dg + (size_t)e * NLOC);
        #pragma unroll
        for (int q = 0; q < 5; ++q)
            od[q] = make_float2(bd[(2*q)*11], bd[(2*q+1)*11]);
    }
    {
        float2* orp = reinterpret_cast<float2*>(out_r0 + (size_t)e * NLOC);
        #pragma unroll
        for (int q = 0; q < 5; ++q)
            orp[q] = make_float2(rr[2*q], rr[2*q+1]);
    }
}

extern "C" void kernel_launch(void* const* d_in, const int* in_sizes, int n_in,
                              void* d_out, int out_size, void* d_ws, size_t ws_size,
                              hipStream_t stream) {
    const float* r0   = (const float*)d_in[0];
    const float* ci   = (const float*)d_in[1];
    const float* cn   = (const float*)d_in[2];
    const float* k    = (const float*)d_in[3];
    const float* dt   = (const float*)d_in[4];
    const float* nmat = (const float*)d_in[5];
    const float* nx   = (const float*)d_in[6];
    const float* dw   = (const float*)d_in[7];
    int nele = in_sizes[7] / NGI;

    float* prodN = (float*)d_ws;
    prodn_kernel<<<(NPAIR * NGI + 127) / 128, 128, 0, stream>>>(nmat, prodN);

    int nb = (nele + 255) / 256;
    fem_kernel<<<nb, 256, 0, stream>>>(r0, ci, cn, k, dt, nx, dw, prodN,
                                       (float*)d_out, nele);
}